// Round 2
// 156.489 us; speedup vs baseline: 1.0236x; 1.0236x over previous
//
#include <hip/hip_runtime.h>
#include <hip/hip_bf16.h>
#include <stdint.h>
#include <stddef.h>

// Problem constants
#define BT_TOK   32768      // B*T
#define IN_DIM   512
#define OUT_DIM  512
#define QDIM     32
#define NG       8
#define NV       8
#define VD       64
#define EPS_G    1e-10f

#define MT       64         // tokens per block (= lanes per wave)
#define NW       8          // waves per block = K-split factor

typedef float f32x2 __attribute__((ext_vector_type(2)));   // native vector for nontemporal store

// ---------------------------------------------------------------------------
// Kernel A: paired codebook-output table
// P2[p][i*8+j][o] = cb[2p][i]@W_post[2p*64:...] + cb[2p+1][j]@W_post[...]
// bf16, 4*64*512 = 256 KB in d_ws. Rebuilt every call (ws is re-poisoned).
// ---------------------------------------------------------------------------
__global__ __launch_bounds__(256) void build_p2(
    const float* __restrict__ codebook,   // (8,8,64)
    const float* __restrict__ W_post,     // (512,512)
    __hip_bfloat16* __restrict__ P2)
{
    const int b  = blockIdx.x;     // 0..255
    const int p  = b >> 6;         // pair 0..3
    const int ij = b & 63;
    const int i  = ij >> 3, j = ij & 7;
    const int t  = threadIdx.x;    // 0..255

    const float* ca  = codebook + ((size_t)(2 * p) * NV + i) * VD;
    const float* cbp = codebook + ((size_t)(2 * p + 1) * NV + j) * VD;
    const float* wa  = W_post + (size_t)(2 * p) * VD * OUT_DIM;
    const float* wb  = W_post + (size_t)(2 * p + 1) * VD * OUT_DIM;

    float a0 = 0.f, a1 = 0.f;
#pragma unroll 8
    for (int d = 0; d < VD; ++d) {
        const float sa = ca[d];            // block-uniform -> scalar
        const float sb = cbp[d];
        a0 += sa * wa[(size_t)d * OUT_DIM + t]       + sb * wb[(size_t)d * OUT_DIM + t];
        a1 += sa * wa[(size_t)d * OUT_DIM + t + 256] + sb * wb[(size_t)d * OUT_DIM + t + 256];
    }
    __hip_bfloat16* dst = P2 + ((size_t)(p * 64 + ij)) * OUT_DIM;
    dst[t]       = __float2bfloat16(a0);
    dst[t + 256] = __float2bfloat16(a1);
}

// ---------------------------------------------------------------------------
// Kernel B: h = x@W_pre+b_pre ; logits = h@W_proj+b_proj ;
//           idx = argmax(logits+gumbel(u)) ; emit packed pair-indices.
// Block: 512 threads = 8 waves, 64 tokens. lane = token; wave = K-eighth.
// x is staged through LDS with fully-coalesced loads (8 full 128B lines per
// float4 instruction) instead of the old 64-line-scatter per-lane row reads.
// The stage buffer overlays each wave's Hs4 slice (per-wave exclusive; DS ops
// complete in order per wave), so LDS stays under 80 KB -> 2 blocks/CU.
// K-accumulation order is bitwise-identical to the previous version.
// ---------------------------------------------------------------------------
__global__ __launch_bounds__(512, 4) void fused_logits(
    const float* __restrict__ x,        // (BT,512)
    const float* __restrict__ W_pre,    // (512,32)
    const float* __restrict__ b_pre,    // (32)
    const float* __restrict__ W_proj,   // (32,64)
    const float* __restrict__ b_proj,   // (64)
    const float* __restrict__ u,        // (BT,64)
    uint32_t* __restrict__ pidx_pack)   // (BT) packed p0|p1<<8|p2<<16|p3<<24
{
    // Per-wave arena: rows 0..63 (token), 36-float stride (b128-aligned, bank
    // conflict-free). Used first as x stage (cols 0..31 = 32 k-values), then
    // overwritten by the partial-h slice (cols 0..31 = 32 j-values).
    __shared__ float Hs4[NW][MT][36];
    __shared__ int   idxs_s[NG][MT];    // argmax per (group, token)

    const int t    = threadIdx.x;
    const int lane = t & 63;                                   // token within block
    const int w    = __builtin_amdgcn_readfirstlane(t >> 6);   // wave id = K-eighth / group
    const int tokbase = blockIdx.x * MT;
    const int gtok    = tokbase + lane;

    // ---------------- Phase 1: partial h over K-slice [w*64, w*64+64) --------
    float acc[QDIM];
#pragma unroll
    for (int j = 0; j < QDIM; ++j) acc[j] = 0.f;

    const int tsub = lane >> 3;          // token sub-index within 8-token group
    const int c4   = lane & 7;           // 16B chunk within the 128B row slice
    const float* xws = x + (size_t)tokbase * IN_DIM + w * 64;  // wave k-slice base

#pragma unroll
    for (int s = 0; s < 2; ++s) {        // 2 stages of 32 k
        // Coalesced stage: instr i covers tokens [8i, 8i+8), 8 lanes per token,
        // each lane one float4 -> 8 full 128B lines per instruction.
        float4 xv[8];
#pragma unroll
        for (int i = 0; i < 8; ++i)
            xv[i] = *(const float4*)(xws + (size_t)(i * 8 + tsub) * IN_DIM + s * 32 + c4 * 4);
#pragma unroll
        for (int i = 0; i < 8; ++i)
            *(float4*)&Hs4[w][i * 8 + tsub][c4 * 4] = xv[i];   // conflict-free (stride 36)

        // Consume: lane reads ITS token's 32 staged k-values (conflict-free),
        // W_pre rows are wave-uniform -> scalar loads. k ascending (same order
        // as previous version -> bitwise-identical h).
        const float* wbase = W_pre + (size_t)(w * 64 + s * 32) * QDIM;
#pragma unroll
        for (int k4 = 0; k4 < 8; ++k4) {
            const float4 xr = *(const float4*)&Hs4[w][lane][k4 * 4];
            const float xk4[4] = {xr.x, xr.y, xr.z, xr.w};
#pragma unroll
            for (int e = 0; e < 4; ++e) {
                const float xvv = xk4[e];
                const float4* wr = (const float4*)(wbase + (size_t)(k4 * 4 + e) * QDIM); // uniform
                const float4 w0 = wr[0], w1 = wr[1], w2 = wr[2], w3 = wr[3];
                const float4 w4 = wr[4], w5 = wr[5], w6 = wr[6], w7 = wr[7];
                acc[0]  += xvv * w0.x; acc[1]  += xvv * w0.y; acc[2]  += xvv * w0.z; acc[3]  += xvv * w0.w;
                acc[4]  += xvv * w1.x; acc[5]  += xvv * w1.y; acc[6]  += xvv * w1.z; acc[7]  += xvv * w1.w;
                acc[8]  += xvv * w2.x; acc[9]  += xvv * w2.y; acc[10] += xvv * w2.z; acc[11] += xvv * w2.w;
                acc[12] += xvv * w3.x; acc[13] += xvv * w3.y; acc[14] += xvv * w3.z; acc[15] += xvv * w3.w;
                acc[16] += xvv * w4.x; acc[17] += xvv * w4.y; acc[18] += xvv * w4.z; acc[19] += xvv * w4.w;
                acc[20] += xvv * w5.x; acc[21] += xvv * w5.y; acc[22] += xvv * w5.z; acc[23] += xvv * w5.w;
                acc[24] += xvv * w6.x; acc[25] += xvv * w6.y; acc[26] += xvv * w6.z; acc[27] += xvv * w6.w;
                acc[28] += xvv * w7.x; acc[29] += xvv * w7.y; acc[30] += xvv * w7.z; acc[31] += xvv * w7.w;
            }
        }
        // Next stage's ds_writes overwrite rows just read: same-wave DS ops are
        // in-order and the compiler preserves may-alias store-after-load order.
    }

    // write partials over the stage data (b128; stride-36 layout conflict-free)
#pragma unroll
    for (int j4 = 0; j4 < 8; ++j4)
        *(float4*)&Hs4[w][lane][j4 * 4] =
            make_float4(acc[j4 * 4], acc[j4 * 4 + 1], acc[j4 * 4 + 2], acc[j4 * 4 + 3]);
    __syncthreads();

    // reduce 8 K-slices in place (each cell owned by exactly one thread)
#pragma unroll
    for (int r = 0; r < 4; ++r) {
        const int id  = t + 512 * r;          // 2048 (tok,j) cells
        const int tok = id >> 5;
        const int j   = id & 31;
        float h = b_pre[j];
#pragma unroll
        for (int q = 0; q < NW; ++q) h += Hs4[q][tok][j];
        Hs4[0][tok][j] = h;
    }
    __syncthreads();

    // ---------------- Phase 2: logits + gumbel + argmax (wave w -> group w) ---
    float h[QDIM];
#pragma unroll
    for (int j4 = 0; j4 < 8; ++j4) {
        const float4 v = *(const float4*)&Hs4[0][lane][j4 * 4];
        h[j4 * 4] = v.x; h[j4 * 4 + 1] = v.y; h[j4 * 4 + 2] = v.z; h[j4 * 4 + 3] = v.w;
    }

    {
        const int g = w;                                // wave-uniform group
        const float4 b0 = *(const float4*)&b_proj[g * 8];
        const float4 b1 = *(const float4*)&b_proj[g * 8 + 4];
        float lg[8] = {b0.x, b0.y, b0.z, b0.w, b1.x, b1.y, b1.z, b1.w};

#pragma unroll
        for (int j = 0; j < QDIM; ++j) {
            const float hv = h[j];
            const float4 a0 = *(const float4*)&W_proj[(size_t)j * 64 + g * 8];     // uniform
            const float4 a1 = *(const float4*)&W_proj[(size_t)j * 64 + g * 8 + 4]; // uniform
            lg[0] += hv * a0.x; lg[1] += hv * a0.y; lg[2] += hv * a0.z; lg[3] += hv * a0.w;
            lg[4] += hv * a1.x; lg[5] += hv * a1.y; lg[6] += hv * a1.z; lg[7] += hv * a1.w;
        }

        const float4 u0 = *(const float4*)&u[(size_t)gtok * 64 + g * 8];
        const float4 u1 = *(const float4*)&u[(size_t)gtok * 64 + g * 8 + 4];
        float y[8];
        y[0] = lg[0] - logf(-logf(u0.x + EPS_G) + EPS_G);
        y[1] = lg[1] - logf(-logf(u0.y + EPS_G) + EPS_G);
        y[2] = lg[2] - logf(-logf(u0.z + EPS_G) + EPS_G);
        y[3] = lg[3] - logf(-logf(u0.w + EPS_G) + EPS_G);
        y[4] = lg[4] - logf(-logf(u1.x + EPS_G) + EPS_G);
        y[5] = lg[5] - logf(-logf(u1.y + EPS_G) + EPS_G);
        y[6] = lg[6] - logf(-logf(u1.z + EPS_G) + EPS_G);
        y[7] = lg[7] - logf(-logf(u1.w + EPS_G) + EPS_G);

        float best = y[0];
        int bi = 0;
#pragma unroll
        for (int v = 1; v < 8; ++v)
            if (y[v] > best) { best = y[v]; bi = v; }   // strict > == np first-max
        idxs_s[g][lane] = bi;
    }
    __syncthreads();

    // pack pair indices: one uint32 per token, coalesced 64-lane store
    if (t < MT) {
        const int tok = t;
        const uint32_t pk =
              (uint32_t)(idxs_s[0][tok] * 8 + idxs_s[1][tok])
            | ((uint32_t)(idxs_s[2][tok] * 8 + idxs_s[3][tok]) << 8)
            | ((uint32_t)(idxs_s[4][tok] * 8 + idxs_s[5][tok]) << 16)
            | ((uint32_t)(idxs_s[6][tok] * 8 + idxs_s[7][tok]) << 24);
        pidx_pack[tokbase + tok] = pk;
    }
}

// ---------------------------------------------------------------------------
// Kernel C: out = b_post + sum_p P2[p][pidx_p]  (standalone gather+store)
// 256 threads / 32 tokens / tiny LDS / low VGPR -> high occupancy.
// Pure L2 gather + streaming nontemporal stores: should run at the HBM write
// roofline instead of the old fused P3's 0.92 TB/s.
// ---------------------------------------------------------------------------
__global__ __launch_bounds__(256) void gather_out(
    const uint32_t* __restrict__ pidx_pack,  // (BT)
    const float* __restrict__ b_post,        // (512)
    const __hip_bfloat16* __restrict__ P2,   // (4,64,512)
    float* __restrict__ out)                 // (BT,512)
{
    __shared__ uint32_t pp[32];
    const int t = threadIdx.x;               // 0..255
    const int tokbase = blockIdx.x * 32;
    if (t < 32) pp[t] = pidx_pack[tokbase + t];
    __syncthreads();

    const int o2 = t * 2;
    const float bp0 = b_post[o2];
    const float bp1 = b_post[o2 + 1];
    const uint32_t* p2u = (const uint32_t*)P2;     // 2 bf16 per uint32
    float* obase = out + (size_t)tokbase * OUT_DIM + o2;

#pragma unroll 4
    for (int tok = 0; tok < 32; ++tok) {
        const uint32_t pk = pp[tok];               // wave-uniform per iteration
        const uint32_t r0 = p2u[(size_t)((pk      ) & 63) * 256 + t];
        const uint32_t r1 = p2u[(size_t)(64  + ((pk >> 8 ) & 63)) * 256 + t];
        const uint32_t r2 = p2u[(size_t)(128 + ((pk >> 16) & 63)) * 256 + t];
        const uint32_t r3 = p2u[(size_t)(192 + ((pk >> 24) & 63)) * 256 + t];
        float s0 = bp0, s1 = bp1;
        s0 += __uint_as_float(r0 << 16); s1 += __uint_as_float(r0 & 0xffff0000u);
        s0 += __uint_as_float(r1 << 16); s1 += __uint_as_float(r1 & 0xffff0000u);
        s0 += __uint_as_float(r2 << 16); s1 += __uint_as_float(r2 & 0xffff0000u);
        s0 += __uint_as_float(r3 << 16); s1 += __uint_as_float(r3 & 0xffff0000u);
        f32x2 sv; sv.x = s0; sv.y = s1;
        __builtin_nontemporal_store(sv, (f32x2*)(obase + (size_t)tok * OUT_DIM));
    }
}

// ---------------------------------------------------------------------------
extern "C" void kernel_launch(void* const* d_in, const int* in_sizes, int n_in,
                              void* d_out, int out_size, void* d_ws, size_t ws_size,
                              hipStream_t stream) {
    const float* x        = (const float*)d_in[0];
    const float* W_pre    = (const float*)d_in[1];
    const float* b_pre    = (const float*)d_in[2];
    const float* W_proj   = (const float*)d_in[3];
    const float* b_proj   = (const float*)d_in[4];
    const float* codebook = (const float*)d_in[5];
    const float* W_post   = (const float*)d_in[6];
    const float* b_post   = (const float*)d_in[7];
    const float* u        = (const float*)d_in[8];
    float* out = (float*)d_out;

    __hip_bfloat16* P2 = (__hip_bfloat16*)d_ws;                       // 256 KB
    uint32_t* pidx     = (uint32_t*)((char*)d_ws + 256 * 1024);       // 128 KB

    build_p2<<<256, 256, 0, stream>>>(codebook, W_post, P2);
    fused_logits<<<BT_TOK / MT, 512, 0, stream>>>(x, W_pre, b_pre, W_proj, b_proj,
                                                  u, pidx);
    gather_out<<<BT_TOK / 32, 256, 0, stream>>>(pidx, b_post, P2, out);
}